// Round 2
// 511.742 us; speedup vs baseline: 1.0613x; 1.0613x over previous
//
#include <hip/hip_runtime.h>

static constexpr int Lp = 128;
static constexpr int Dp = 768;
static constexpr int Bp = 8;
static constexpr int CELLS = Bp * Lp * Lp;   // 131072
static constexpr int LL = Lp * Lp;           // 16384
static constexpr int BLOCKS = 4096;          // logits kernel blocks
static constexpr int CPW = 8;                // cells per wave (4096*4*8 == CELLS)

typedef float f4 __attribute__((ext_vector_type(4)));  // native vector: OK for nontemporal builtins

__device__ __forceinline__ float dot4(f4 a, f4 w) {
    return a.x * w.x + a.y * w.y + a.z * w.z + a.w * w.w;
}

// 4096 blocks x 256 threads. Each wave: 8 cells, 4 at a time, 12 nontemporal
// float4 loads in flight before any use. Reduce-scatter butterfly (offsets
// 1,2,4 exchange-halve; 8,16,32 plain reduce) = 10 swizzles per chunk instead
// of 48, leaving total S0..S3 on lanes 0..3 and E0..E3 on lanes 4..7. The 8
// epilogues (exp/log1p) run on 8 parallel lanes; pred store is one instruction
// covering two coalesced 16B segments (predS quad + predE quad).
__global__ __launch_bounds__(256, 4) void logits_loss_kernel(
    const float* __restrict__ table,
    const int* __restrict__ labS,
    const int* __restrict__ labE,
    const float* __restrict__ WS, const float* __restrict__ bSp,
    const float* __restrict__ WE, const float* __restrict__ bEp,
    float* __restrict__ out,
    float2* __restrict__ partial)
{
    const int lane = threadIdx.x & 63;
    const int wid  = threadIdx.x >> 6;
    const int gwave = blockIdx.x * 4 + wid;
    const int cell0 = gwave * CPW;

    const f4* wS4 = (const f4*)WS;
    const f4* wE4 = (const f4*)WE;
    const f4 ws0 = wS4[lane], ws1 = wS4[lane + 64], ws2 = wS4[lane + 128];
    const f4 we0 = wE4[lane], we1 = wE4[lane + 64], we2 = wE4[lane + 128];
    const float bs = bSp[0], be = bEp[0];

    // Epilogue lane mapping: c = lane&3 (cell within chunk), isE = lane bit2.
    const int c    = lane & 3;
    const int isE  = lane & 4;
    // Per-lane label preload (lanes 0..7 only): wl* = labS (weight source for
    // BOTH heads, as in reference), tl* = target label for this lane's head.
    int wl0 = 0, wl1 = 0, tl0 = 0, tl1 = 0;
    if (lane < 8) {
        wl0 = labS[cell0 + c];
        wl1 = labS[cell0 + 4 + c];
        tl0 = isE ? labE[cell0 + c]     : wl0;
        tl1 = isE ? labE[cell0 + 4 + c] : wl1;
    }

    float* __restrict__ predS = out + 2;
    float* __restrict__ predE = out + 2 + CELLS;
    const float bias = isE ? be : bs;
    float* __restrict__ predP = isE ? predE : predS;

    float acc = 0.f;   // S-loss partial on lanes 0..3, E-loss partial on 4..7
    const f4* t4 = (const f4*)table + (size_t)cell0 * 192;

    for (int i = 0; i < CPW; i += 4) {
        const f4* p = t4 + (size_t)i * 192;
        f4 a0 = __builtin_nontemporal_load(p + lane);
        f4 a1 = __builtin_nontemporal_load(p + lane + 64);
        f4 a2 = __builtin_nontemporal_load(p + lane + 128);
        f4 b0v = __builtin_nontemporal_load(p + lane + 192);
        f4 b1v = __builtin_nontemporal_load(p + lane + 256);
        f4 b2v = __builtin_nontemporal_load(p + lane + 320);
        f4 g0 = __builtin_nontemporal_load(p + lane + 384);
        f4 g1 = __builtin_nontemporal_load(p + lane + 448);
        f4 g2 = __builtin_nontemporal_load(p + lane + 512);
        f4 d0 = __builtin_nontemporal_load(p + lane + 576);
        f4 d1 = __builtin_nontemporal_load(p + lane + 640);
        f4 d2 = __builtin_nontemporal_load(p + lane + 704);

        float s0 = dot4(a0, ws0) + dot4(a1, ws1) + dot4(a2, ws2);
        float e0 = dot4(a0, we0) + dot4(a1, we1) + dot4(a2, we2);
        float s1 = dot4(b0v, ws0) + dot4(b1v, ws1) + dot4(b2v, ws2);
        float e1 = dot4(b0v, we0) + dot4(b1v, we1) + dot4(b2v, we2);
        float s2 = dot4(g0, ws0) + dot4(g1, ws1) + dot4(g2, ws2);
        float e2 = dot4(g0, we0) + dot4(g1, we1) + dot4(g2, we2);
        float s3 = dot4(d0, ws0) + dot4(d1, ws1) + dot4(d2, ws2);
        float e3 = dot4(d0, we0) + dot4(d1, we1) + dot4(d2, we2);

        // Reduce-scatter butterfly: class v = (isE<<2)|c ends on lanes with
        // (lane&7)==v. Level k keeps the value whose class-bit matches the
        // lane's bit, sends the other; 10 swizzles total.
        const int bb0 = lane & 1;
        const int bb1 = lane & 2;
        float t, sA, sB, eA, eB, S, E, v;
        t = __shfl_xor(bb0 ? s0 : s1, 1); sA = (bb0 ? s1 : s0) + t; // S_{bb0}
        t = __shfl_xor(bb0 ? s2 : s3, 1); sB = (bb0 ? s3 : s2) + t; // S_{2+bb0}
        t = __shfl_xor(bb0 ? e0 : e1, 1); eA = (bb0 ? e1 : e0) + t; // E_{bb0}
        t = __shfl_xor(bb0 ? e2 : e3, 1); eB = (bb0 ? e3 : e2) + t; // E_{2+bb0}
        t = __shfl_xor(bb1 ? sA : sB, 2); S = (bb1 ? sB : sA) + t;  // S_{lane&3}
        t = __shfl_xor(bb1 ? eA : eB, 2); E = (bb1 ? eB : eA) + t;  // E_{lane&3}
        t = __shfl_xor(isE ? S : E, 4);   v = (isE ? E : S) + t;    // V_{lane&7}
        v += __shfl_xor(v, 8);
        v += __shfl_xor(v, 16);
        v += __shfl_xor(v, 32);

        if (lane < 8) {
            const int cc = cell0 + i + c;
            const int wl = (i == 0) ? wl0 : wl1;
            const int tl = (i == 0) ? tl0 : tl1;
            float x = v + bias;
            float w = (wl >= 0) ? 1.0f : 0.0f;
            float ex = expf(-fabsf(x));
            acc += w * (fmaxf(x, 0.f) + log1pf(ex) - x * (float)tl);
            predP[cc] = w * ((x >= 0.f ? 1.f : ex) / (1.f + ex)); // 2x coalesced quad
        }
    }

    // Fold the 4-lane groups: lane 0 ends with S total, lane 4 with E total.
    acc += __shfl_xor(acc, 1);
    acc += __shfl_xor(acc, 2);

    __shared__ float redS[4], redE[4];
    if (lane == 0) redS[wid] = acc;
    else if (lane == 4) redE[wid] = acc;
    __syncthreads();
    if (threadIdx.x == 0) {
        float2 pr;
        pr.x = redS[0] + redS[1] + redS[2] + redS[3];
        pr.y = redE[0] + redE[1] + redE[2] + redE[3];
        partial[blockIdx.x] = pr;
    }
}

// One block per (head, batch). 1024-bin value-space select; zeros counted via
// ballot (no same-address LDS atomic storm). I/O vectorized as float2 (pred
// arrays start at byte offset 8 -> 16B alignment unavailable). Block 0 also
// folds in the loss reduction on its first 256 threads (saves a launch).
__global__ __launch_bounds__(1024) void topk_predict_kernel(
    const int* __restrict__ attn, float* __restrict__ out,
    const float2* __restrict__ partial)
{
    const int b    = blockIdx.x & 7;
    const int head = blockIdx.x >> 3;
    float* arr = out + 2 + head * CELLS + b * LL;
    const int tid = threadIdx.x;

    __shared__ unsigned hist[1024];
    __shared__ unsigned cand[2048];
    __shared__ unsigned sh_B, sh_kk, sh_thr, sh_ccnt;
    __shared__ float shS[4], shE[4];

    hist[tid] = 0u;
    if (tid == 0) { sh_ccnt = 0u; sh_thr = 0x7F800000u; }

    // fused loss reduce (block 0, waves 0..3 only; no barrier inside)
    if (blockIdx.x == 0 && tid < 256) {
        float s = 0.f, e = 0.f;
        for (int i = tid; i < BLOCKS; i += 256) {
            float2 p = partial[i];
            s += p.x; e += p.y;
        }
        #pragma unroll
        for (int off = 32; off; off >>= 1) {
            s += __shfl_down(s, off);
            e += __shfl_down(e, off);
        }
        if ((tid & 63) == 0) { shS[tid >> 6] = s; shE[tid >> 6] = e; }
    }
    __syncthreads();
    if (blockIdx.x == 0 && tid == 0) {
        const float inv = 1.0f / (float)CELLS;
        out[0] = (shS[0] + shS[1] + shS[2] + shS[3]) * inv;
        out[1] = (shE[0] + shE[1] + shE[2] + shE[3]) * inv;
    }

    const float2* a2 = (const float2*)arr;
    float2 fv[8];
    #pragma unroll
    for (int j = 0; j < 8; j++) fv[j] = a2[tid + j * 1024];

    unsigned vu[16];
    int bk[16];
    int zc = 0;
    #pragma unroll
    for (int j = 0; j < 8; j++) {
        float f0 = fv[j].x, f1 = fv[j].y;
        vu[2*j]   = __float_as_uint(f0);
        vu[2*j+1] = __float_as_uint(f1);
        if (f0 > 0.0f) {
            int bb = (int)(f0 * 1024.0f);
            bk[2*j] = bb > 1023 ? 1023 : bb;
            atomicAdd(&hist[bk[2*j]], 1u);
        } else { bk[2*j] = 0; zc++; }
        if (f1 > 0.0f) {
            int bb = (int)(f1 * 1024.0f);
            bk[2*j+1] = bb > 1023 ? 1023 : bb;
            atomicAdd(&hist[bk[2*j+1]], 1u);
        } else { bk[2*j+1] = 0; zc++; }
    }
    #pragma unroll
    for (int off = 32; off; off >>= 1) zc += __shfl_down(zc, off);
    if ((tid & 63) == 0 && zc) atomicAdd(&hist[0], (unsigned)zc);
    __syncthreads();

    if (tid < 64) {
        const int lane = tid;
        int m = attn[b * Lp + lane] + attn[b * Lp + 64 + lane];
        #pragma unroll
        for (int off = 32; off; off >>= 1) m += __shfl_down(m, off);
        m = __shfl(m, 0);
        int ml  = m - 2;
        int len = (int)((float)ml * 0.3f);
        len = len > 5 ? len : 5;
        int cap = ml * ml;
        len = len < cap ? len : cap;
        const unsigned k = (unsigned)len;

        unsigned h[16], s = 0u;
        #pragma unroll
        for (int j = 0; j < 16; j++) { h[j] = hist[16 * lane + j]; s += h[j]; }
        unsigned suf = s;
        #pragma unroll
        for (int off = 1; off < 64; off <<= 1) {
            unsigned t = __shfl_down(suf, off);
            if (lane + off < 64) suf += t;
        }
        unsigned run = suf - s;          // suffix just above this lane's bins
        int best = -1; unsigned snext = 0u;
        #pragma unroll
        for (int j = 15; j >= 0; j--) {
            unsigned nr = run + h[j];    // suffix at bin 16*lane+j
            if (best < 0 && nr >= k) { best = 16 * lane + j; snext = run; }
            run = nr;
        }
        unsigned long long msk = __ballot(best >= 0);
        int blane = 63 - __clzll(msk);
        if (lane == blane) { sh_B = (unsigned)best; sh_kk = k - snext; }
    }
    __syncthreads();

    const int B = (int)sh_B;
    const unsigned kk = sh_kk;

    #pragma unroll
    for (int i = 0; i < 16; i++) {
        if (bk[i] == B) {
            unsigned idx = atomicAdd(&sh_ccnt, 1u);
            if (idx < 2048u) cand[idx] = vu[i];
        }
    }
    __syncthreads();

    const unsigned C = sh_ccnt < 2048u ? sh_ccnt : 2048u;
    for (unsigned j = tid; j < C; j += 1024) {
        unsigned x = cand[j], g = 0u;
        for (unsigned i2 = 0; i2 < C; ++i2) g += (cand[i2] > x) ? 1u : 0u;
        if (g < kk) atomicMin(&sh_thr, x);
    }
    __syncthreads();

    const unsigned thr = sh_thr;
    float2* w2 = (float2*)arr;
    #pragma unroll
    for (int j = 0; j < 8; j++) {
        float2 r;
        r.x = (vu[2*j]   >= thr) ? 1.0f : 0.0f;
        r.y = (vu[2*j+1] >= thr) ? 1.0f : 0.0f;
        w2[tid + j * 1024] = r;
    }
}

extern "C" void kernel_launch(void* const* d_in, const int* in_sizes, int n_in,
                              void* d_out, int out_size, void* d_ws, size_t ws_size,
                              hipStream_t stream) {
    const float* table = (const float*)d_in[0];
    const int*   attn  = (const int*)d_in[1];
    const int*   labS  = (const int*)d_in[2];
    const int*   labE  = (const int*)d_in[3];
    const float* WS    = (const float*)d_in[4];
    const float* bS    = (const float*)d_in[5];
    const float* WE    = (const float*)d_in[6];
    const float* bE    = (const float*)d_in[7];
    float* out = (float*)d_out;
    float2* partial = (float2*)d_ws;

    logits_loss_kernel<<<BLOCKS, 256, 0, stream>>>(table, labS, labE, WS, bS, WE, bE,
                                                   out, partial);
    topk_predict_kernel<<<16, 1024, 0, stream>>>(attn, out, partial);
}

// Round 3
// 509.301 us; speedup vs baseline: 1.0664x; 1.0048x over previous
//
#include <hip/hip_runtime.h>

static constexpr int Lp = 128;
static constexpr int Dp = 768;
static constexpr int Bp = 8;
static constexpr int CELLS = Bp * Lp * Lp;   // 131072
static constexpr int LL = Lp * Lp;           // 16384
static constexpr int BLOCKS = 4096;          // logits kernel blocks
static constexpr int CPW = 8;                // cells per wave (4096*4*8 == CELLS)

typedef float f4 __attribute__((ext_vector_type(4)));  // native vector: OK for nontemporal builtins

__device__ __forceinline__ float dot4(f4 a, f4 w) {
    return a.x * w.x + a.y * w.y + a.z * w.z + a.w * w.w;
}

__device__ __forceinline__ void load12(const f4* p, int lane, f4 v[12]) {
    #pragma unroll
    for (int j = 0; j < 12; j++) v[j] = __builtin_nontemporal_load(p + lane + j * 64);
}

__device__ __forceinline__ void dots8(const f4 v[12], const f4 ws[3], const f4 we[3],
                                      float s[4], float e[4]) {
    #pragma unroll
    for (int c2 = 0; c2 < 4; c2++) {
        s[c2] = dot4(v[3*c2], ws[0]) + dot4(v[3*c2+1], ws[1]) + dot4(v[3*c2+2], ws[2]);
        e[c2] = dot4(v[3*c2], we[0]) + dot4(v[3*c2+1], we[1]) + dot4(v[3*c2+2], we[2]);
    }
}

// Reduce-scatter butterfly: class v = (isE<<2)|(lane&3) ends on lanes with
// (lane&7)==class. 10 swizzles total (vs 48 for full 8-value butterfly).
__device__ __forceinline__ float reduce8(const float s[4], const float e[4],
                                         int lane, int isE) {
    const int bb0 = lane & 1;
    const int bb1 = lane & 2;
    float t, sA, sB, eA, eB, S, E, v;
    t = __shfl_xor(bb0 ? s[0] : s[1], 1); sA = (bb0 ? s[1] : s[0]) + t;
    t = __shfl_xor(bb0 ? s[2] : s[3], 1); sB = (bb0 ? s[3] : s[2]) + t;
    t = __shfl_xor(bb0 ? e[0] : e[1], 1); eA = (bb0 ? e[1] : e[0]) + t;
    t = __shfl_xor(bb0 ? e[2] : e[3], 1); eB = (bb0 ? e[3] : e[2]) + t;
    t = __shfl_xor(bb1 ? sA : sB, 2); S = (bb1 ? sB : sA) + t;
    t = __shfl_xor(bb1 ? eA : eB, 2); E = (bb1 ? eB : eA) + t;
    t = __shfl_xor(isE ? S : E, 4);   v = (isE ? E : S) + t;
    v += __shfl_xor(v, 8);
    v += __shfl_xor(v, 16);
    v += __shfl_xor(v, 32);
    return v;
}

__device__ __forceinline__ void epi8(float v, float bias, int wl, int tl, int lane,
                                     float* __restrict__ predP, int cc, float& acc) {
    if (lane < 8) {
        float x = v + bias;
        float w = (wl >= 0) ? 1.0f : 0.0f;
        float ex = expf(-fabsf(x));
        acc += w * (fmaxf(x, 0.f) + log1pf(ex) - x * (float)tl);
        predP[cc] = w * ((x >= 0.f ? 1.f : ex) / (1.f + ex)); // 2x coalesced 16B quad
    }
}

// 4096 blocks x 256 threads. Each wave: 8 cells as two 4-cell chunks,
// EXPLICITLY software-pipelined: chunk-B's 12 nontemporal float4 loads are
// issued between chunk-A's FMAs (which kill A's staging registers) and
// chunk-A's butterfly+epilogue, so B's HBM latency hides under A's reduce.
// Peak staging pressure stays ~1 chunk (48 VGPR) + weights (24).
__global__ __launch_bounds__(256, 4) void logits_loss_kernel(
    const float* __restrict__ table,
    const int* __restrict__ labS,
    const int* __restrict__ labE,
    const float* __restrict__ WS, const float* __restrict__ bSp,
    const float* __restrict__ WE, const float* __restrict__ bEp,
    float* __restrict__ out,
    float2* __restrict__ partial)
{
    const int lane = threadIdx.x & 63;
    const int wid  = threadIdx.x >> 6;
    const int gwave = blockIdx.x * 4 + wid;
    const int cell0 = gwave * CPW;

    const f4* wS4 = (const f4*)WS;
    const f4* wE4 = (const f4*)WE;
    f4 ws[3], we[3];
    #pragma unroll
    for (int j = 0; j < 3; j++) { ws[j] = wS4[lane + j * 64]; we[j] = wE4[lane + j * 64]; }
    const float bs = bSp[0], be = bEp[0];

    // Epilogue lane mapping: c = lane&3 (cell within chunk), isE = lane bit2.
    const int c    = lane & 3;
    const int isE  = lane & 4;
    int wl0 = 0, wl1 = 0, tl0 = 0, tl1 = 0;
    if (lane < 8) {
        wl0 = labS[cell0 + c];
        wl1 = labS[cell0 + 4 + c];
        tl0 = isE ? labE[cell0 + c]     : wl0;
        tl1 = isE ? labE[cell0 + 4 + c] : wl1;
    }

    float* __restrict__ predS = out + 2;
    float* __restrict__ predE = out + 2 + CELLS;
    const float bias = isE ? be : bs;
    float* __restrict__ predP = isE ? predE : predS;

    float acc = 0.f;   // S-loss partial on lanes 0..3, E-loss partial on 4..7
    const f4* t4 = (const f4*)table + (size_t)cell0 * 192;

    // ---- chunk A: cells 0..3 ----
    f4 vA[12];
    load12(t4, lane, vA);
    float sA_[4], eA_[4];
    dots8(vA, ws, we, sA_, eA_);          // consumes vA -> registers free

    // ---- chunk B loads in flight during A's reduce/epilogue ----
    f4 vB[12];
    load12(t4 + 4 * 192, lane, vB);

    float xA = reduce8(sA_, eA_, lane, isE);
    epi8(xA, bias, wl0, tl0, lane, predP, cell0 + c, acc);

    float sB_[4], eB_[4];
    dots8(vB, ws, we, sB_, eB_);
    float xB = reduce8(sB_, eB_, lane, isE);
    epi8(xB, bias, wl1, tl1, lane, predP, cell0 + 4 + c, acc);

    // Fold the 4-lane groups: lane 0 ends with S total, lane 4 with E total.
    acc += __shfl_xor(acc, 1);
    acc += __shfl_xor(acc, 2);

    __shared__ float redS[4], redE[4];
    if (lane == 0) redS[wid] = acc;
    else if (lane == 4) redE[wid] = acc;
    __syncthreads();
    if (threadIdx.x == 0) {
        float2 pr;
        pr.x = redS[0] + redS[1] + redS[2] + redS[3];
        pr.y = redE[0] + redE[1] + redE[2] + redE[3];
        partial[blockIdx.x] = pr;
    }
}

// One block per (head, batch). 1024-bin value-space select; zeros counted via
// ballot. Pred loads hoisted to the very top so their HBM/L3 latency hides
// under hist-zeroing + fused loss reduce + first barrier. I/O as float2
// (pred arrays start at byte offset 8 -> 16B alignment unavailable).
__global__ __launch_bounds__(1024) void topk_predict_kernel(
    const int* __restrict__ attn, float* __restrict__ out,
    const float2* __restrict__ partial)
{
    const int b    = blockIdx.x & 7;
    const int head = blockIdx.x >> 3;
    float* arr = out + 2 + head * CELLS + b * LL;
    const int tid = threadIdx.x;

    // issue pred loads FIRST (latency hidden under everything below)
    const float2* a2 = (const float2*)arr;
    float2 fv[8];
    #pragma unroll
    for (int j = 0; j < 8; j++) fv[j] = a2[tid + j * 1024];

    __shared__ unsigned hist[1024];
    __shared__ unsigned cand[2048];
    __shared__ unsigned sh_B, sh_kk, sh_thr, sh_ccnt;
    __shared__ float shS[4], shE[4];

    hist[tid] = 0u;
    if (tid == 0) { sh_ccnt = 0u; sh_thr = 0x7F800000u; }

    // fused loss reduce (block 0, waves 0..3 only; no barrier inside)
    if (blockIdx.x == 0 && tid < 256) {
        float s = 0.f, e = 0.f;
        for (int i = tid; i < BLOCKS; i += 256) {
            float2 p = partial[i];
            s += p.x; e += p.y;
        }
        #pragma unroll
        for (int off = 32; off; off >>= 1) {
            s += __shfl_down(s, off);
            e += __shfl_down(e, off);
        }
        if ((tid & 63) == 0) { shS[tid >> 6] = s; shE[tid >> 6] = e; }
    }
    __syncthreads();
    if (blockIdx.x == 0 && tid == 0) {
        const float inv = 1.0f / (float)CELLS;
        out[0] = (shS[0] + shS[1] + shS[2] + shS[3]) * inv;
        out[1] = (shE[0] + shE[1] + shE[2] + shE[3]) * inv;
    }

    unsigned vu[16];
    int bk[16];
    int zc = 0;
    #pragma unroll
    for (int j = 0; j < 8; j++) {
        float f0 = fv[j].x, f1 = fv[j].y;
        vu[2*j]   = __float_as_uint(f0);
        vu[2*j+1] = __float_as_uint(f1);
        if (f0 > 0.0f) {
            int bb = (int)(f0 * 1024.0f);
            bk[2*j] = bb > 1023 ? 1023 : bb;
            atomicAdd(&hist[bk[2*j]], 1u);
        } else { bk[2*j] = 0; zc++; }
        if (f1 > 0.0f) {
            int bb = (int)(f1 * 1024.0f);
            bk[2*j+1] = bb > 1023 ? 1023 : bb;
            atomicAdd(&hist[bk[2*j+1]], 1u);
        } else { bk[2*j+1] = 0; zc++; }
    }
    #pragma unroll
    for (int off = 32; off; off >>= 1) zc += __shfl_down(zc, off);
    if ((tid & 63) == 0 && zc) atomicAdd(&hist[0], (unsigned)zc);
    __syncthreads();

    if (tid < 64) {
        const int lane = tid;
        int m = attn[b * Lp + lane] + attn[b * Lp + 64 + lane];
        #pragma unroll
        for (int off = 32; off; off >>= 1) m += __shfl_down(m, off);
        m = __shfl(m, 0);
        int ml  = m - 2;
        int len = (int)((float)ml * 0.3f);
        len = len > 5 ? len : 5;
        int cap = ml * ml;
        len = len < cap ? len : cap;
        const unsigned k = (unsigned)len;

        unsigned h[16], s = 0u;
        #pragma unroll
        for (int j = 0; j < 16; j++) { h[j] = hist[16 * lane + j]; s += h[j]; }
        unsigned suf = s;
        #pragma unroll
        for (int off = 1; off < 64; off <<= 1) {
            unsigned t = __shfl_down(suf, off);
            if (lane + off < 64) suf += t;
        }
        unsigned run = suf - s;          // suffix just above this lane's bins
        int best = -1; unsigned snext = 0u;
        #pragma unroll
        for (int j = 15; j >= 0; j--) {
            unsigned nr = run + h[j];    // suffix at bin 16*lane+j
            if (best < 0 && nr >= k) { best = 16 * lane + j; snext = run; }
            run = nr;
        }
        unsigned long long msk = __ballot(best >= 0);
        int blane = 63 - __clzll(msk);
        if (lane == blane) { sh_B = (unsigned)best; sh_kk = k - snext; }
    }
    __syncthreads();

    const int B = (int)sh_B;
    const unsigned kk = sh_kk;

    #pragma unroll
    for (int i = 0; i < 16; i++) {
        if (bk[i] == B) {
            unsigned idx = atomicAdd(&sh_ccnt, 1u);
            if (idx < 2048u) cand[idx] = vu[i];
        }
    }
    __syncthreads();

    const unsigned C = sh_ccnt < 2048u ? sh_ccnt : 2048u;
    for (unsigned j = tid; j < C; j += 1024) {
        unsigned x = cand[j], g = 0u;
        for (unsigned i2 = 0; i2 < C; ++i2) g += (cand[i2] > x) ? 1u : 0u;
        if (g < kk) atomicMin(&sh_thr, x);
    }
    __syncthreads();

    const unsigned thr = sh_thr;
    float2* w2 = (float2*)arr;
    #pragma unroll
    for (int j = 0; j < 8; j++) {
        float2 r;
        r.x = (vu[2*j]   >= thr) ? 1.0f : 0.0f;
        r.y = (vu[2*j+1] >= thr) ? 1.0f : 0.0f;
        w2[tid + j * 1024] = r;
    }
}

extern "C" void kernel_launch(void* const* d_in, const int* in_sizes, int n_in,
                              void* d_out, int out_size, void* d_ws, size_t ws_size,
                              hipStream_t stream) {
    const float* table = (const float*)d_in[0];
    const int*   attn  = (const int*)d_in[1];
    const int*   labS  = (const int*)d_in[2];
    const int*   labE  = (const int*)d_in[3];
    const float* WS    = (const float*)d_in[4];
    const float* bS    = (const float*)d_in[5];
    const float* WE    = (const float*)d_in[6];
    const float* bE    = (const float*)d_in[7];
    float* out = (float*)d_out;
    float2* partial = (float2*)d_ws;

    logits_loss_kernel<<<BLOCKS, 256, 0, stream>>>(table, labS, labE, WS, bS, WE, bE,
                                                   out, partial);
    topk_predict_kernel<<<16, 1024, 0, stream>>>(attn, out, partial);
}

// Round 4
// 508.462 us; speedup vs baseline: 1.0682x; 1.0017x over previous
//
#include <hip/hip_runtime.h>

static constexpr int Lp = 128;
static constexpr int Dp = 768;
static constexpr int Bp = 8;
static constexpr int CELLS = Bp * Lp * Lp;   // 131072
static constexpr int LL = Lp * Lp;           // 16384
static constexpr int BLOCKS = 1024;          // logits kernel blocks (exactly 4/CU -> ONE round)
static constexpr int CPW = 32;               // cells per wave (1024*4*32 == CELLS)

typedef float f4 __attribute__((ext_vector_type(4)));  // native vector: OK for nontemporal builtins

__device__ __forceinline__ float dot4(f4 a, f4 w) {
    return a.x * w.x + a.y * w.y + a.z * w.z + a.w * w.w;
}

__device__ __forceinline__ void load12(const f4* p, int lane, f4 v[12]) {
    #pragma unroll
    for (int j = 0; j < 12; j++) v[j] = __builtin_nontemporal_load(p + lane + j * 64);
}

__device__ __forceinline__ void dots8(const f4 v[12], const f4 ws[3], const f4 we[3],
                                      float s[4], float e[4]) {
    #pragma unroll
    for (int c2 = 0; c2 < 4; c2++) {
        s[c2] = dot4(v[3*c2], ws[0]) + dot4(v[3*c2+1], ws[1]) + dot4(v[3*c2+2], ws[2]);
        e[c2] = dot4(v[3*c2], we[0]) + dot4(v[3*c2+1], we[1]) + dot4(v[3*c2+2], we[2]);
    }
}

// Reduce-scatter butterfly: class v = (isE<<2)|(lane&3) ends on lanes with
// (lane&7)==class. 10 swizzles total (vs 48 for full 8-value butterfly).
__device__ __forceinline__ float reduce8(const float s[4], const float e[4],
                                         int lane, int isE) {
    const int bb0 = lane & 1;
    const int bb1 = lane & 2;
    float t, sA, sB, eA, eB, S, E, v;
    t = __shfl_xor(bb0 ? s[0] : s[1], 1); sA = (bb0 ? s[1] : s[0]) + t;
    t = __shfl_xor(bb0 ? s[2] : s[3], 1); sB = (bb0 ? s[3] : s[2]) + t;
    t = __shfl_xor(bb0 ? e[0] : e[1], 1); eA = (bb0 ? e[1] : e[0]) + t;
    t = __shfl_xor(bb0 ? e[2] : e[3], 1); eB = (bb0 ? e[3] : e[2]) + t;
    t = __shfl_xor(bb1 ? sA : sB, 2); S = (bb1 ? sB : sA) + t;
    t = __shfl_xor(bb1 ? eA : eB, 2); E = (bb1 ? eB : eA) + t;
    t = __shfl_xor(isE ? S : E, 4);   v = (isE ? E : S) + t;
    v += __shfl_xor(v, 8);
    v += __shfl_xor(v, 16);
    v += __shfl_xor(v, 32);
    return v;
}

// 1024 blocks x 256 threads, ONE resident round (4 blocks/CU). Each wave
// streams 32 cells as 8 fully-unrolled 4-cell chunks: per-wave prologue
// (6 weight vector loads, label preload, addressing) amortized 4x better
// than the 4096-block version. Labels preloaded coalesced across all 64
// lanes (0-31: labS, 32-63: labE), delivered per-chunk via 2 bpermutes.
__global__ __launch_bounds__(256, 4) void logits_loss_kernel(
    const float* __restrict__ table,
    const int* __restrict__ labS,
    const int* __restrict__ labE,
    const float* __restrict__ WS, const float* __restrict__ bSp,
    const float* __restrict__ WE, const float* __restrict__ bEp,
    float* __restrict__ out,
    float2* __restrict__ partial)
{
    const int lane = threadIdx.x & 63;
    const int wid  = threadIdx.x >> 6;
    const int gwave = blockIdx.x * 4 + wid;
    const int cell0 = gwave * CPW;

    const f4* wS4 = (const f4*)WS;
    const f4* wE4 = (const f4*)WE;
    f4 ws[3], we[3];
    #pragma unroll
    for (int j = 0; j < 3; j++) { ws[j] = wS4[lane + j * 64]; we[j] = wE4[lane + j * 64]; }
    const float bs = bSp[0], be = bEp[0];

    // Epilogue lane mapping: c = lane&3 (cell within chunk), isE = lane bit2.
    const int c    = lane & 3;
    const int isE  = lane & 4;

    // Coalesced label preload: lanes 0..31 hold labS[cell0+lane],
    // lanes 32..63 hold labE[cell0+lane-32].
    const int labval = (lane < 32) ? labS[cell0 + lane] : labE[cell0 + lane - 32];

    float* __restrict__ predS = out + 2;
    float* __restrict__ predE = out + 2 + CELLS;
    const float bias = isE ? be : bs;
    float* __restrict__ predP = isE ? predE : predS;

    float acc = 0.f;   // S-loss partial on lanes 0..3, E-loss partial on 4..7
    const f4* t4 = (const f4*)table + (size_t)cell0 * 192;

    #pragma unroll
    for (int i = 0; i < 8; i++) {
        const f4* p = t4 + (size_t)i * 768;   // 4 cells x 192 f4
        f4 v[12];
        load12(p, lane, v);
        float s[4], e[4];
        dots8(v, ws, we, s, e);
        float x = reduce8(s, e, lane, isE) + bias;

        const int wlv = __shfl(labval, 4 * i + c);        // labS (weight, both heads)
        const int tlv = __shfl(labval, 32 + 4 * i + c);   // labE
        if (lane < 8) {
            const int tl = isE ? tlv : wlv;
            const float w = (wlv >= 0) ? 1.0f : 0.0f;
            const float ex = expf(-fabsf(x));
            acc += w * (fmaxf(x, 0.f) + log1pf(ex) - x * (float)tl);
            predP[cell0 + 4 * i + c] = w * ((x >= 0.f ? 1.f : ex) / (1.f + ex));
        }
    }

    // Fold the 4-lane groups: lane 0 ends with S total, lane 4 with E total.
    acc += __shfl_xor(acc, 1);
    acc += __shfl_xor(acc, 2);

    __shared__ float redS[4], redE[4];
    if (lane == 0) redS[wid] = acc;
    else if (lane == 4) redE[wid] = acc;
    __syncthreads();
    if (threadIdx.x == 0) {
        float2 pr;
        pr.x = redS[0] + redS[1] + redS[2] + redS[3];
        pr.y = redE[0] + redE[1] + redE[2] + redE[3];
        partial[blockIdx.x] = pr;
    }
}

// One block per (head, batch). 1024-bin value-space select; zeros counted via
// ballot. Pred loads hoisted to the very top so their HBM/L3 latency hides
// under hist-zeroing + fused loss reduce + first barrier. I/O as float2
// (pred arrays start at byte offset 8 -> 16B alignment unavailable).
__global__ __launch_bounds__(1024) void topk_predict_kernel(
    const int* __restrict__ attn, float* __restrict__ out,
    const float2* __restrict__ partial)
{
    const int b    = blockIdx.x & 7;
    const int head = blockIdx.x >> 3;
    float* arr = out + 2 + head * CELLS + b * LL;
    const int tid = threadIdx.x;

    // issue pred loads FIRST (latency hidden under everything below)
    const float2* a2 = (const float2*)arr;
    float2 fv[8];
    #pragma unroll
    for (int j = 0; j < 8; j++) fv[j] = a2[tid + j * 1024];

    __shared__ unsigned hist[1024];
    __shared__ unsigned cand[2048];
    __shared__ unsigned sh_B, sh_kk, sh_thr, sh_ccnt;
    __shared__ float shS[4], shE[4];

    hist[tid] = 0u;
    if (tid == 0) { sh_ccnt = 0u; sh_thr = 0x7F800000u; }

    // fused loss reduce (block 0, waves 0..3 only; no barrier inside)
    if (blockIdx.x == 0 && tid < 256) {
        float s = 0.f, e = 0.f;
        for (int i = tid; i < BLOCKS; i += 256) {
            float2 p = partial[i];
            s += p.x; e += p.y;
        }
        #pragma unroll
        for (int off = 32; off; off >>= 1) {
            s += __shfl_down(s, off);
            e += __shfl_down(e, off);
        }
        if ((tid & 63) == 0) { shS[tid >> 6] = s; shE[tid >> 6] = e; }
    }
    __syncthreads();
    if (blockIdx.x == 0 && tid == 0) {
        const float inv = 1.0f / (float)CELLS;
        out[0] = (shS[0] + shS[1] + shS[2] + shS[3]) * inv;
        out[1] = (shE[0] + shE[1] + shE[2] + shE[3]) * inv;
    }

    unsigned vu[16];
    int bk[16];
    int zc = 0;
    #pragma unroll
    for (int j = 0; j < 8; j++) {
        float f0 = fv[j].x, f1 = fv[j].y;
        vu[2*j]   = __float_as_uint(f0);
        vu[2*j+1] = __float_as_uint(f1);
        if (f0 > 0.0f) {
            int bb = (int)(f0 * 1024.0f);
            bk[2*j] = bb > 1023 ? 1023 : bb;
            atomicAdd(&hist[bk[2*j]], 1u);
        } else { bk[2*j] = 0; zc++; }
        if (f1 > 0.0f) {
            int bb = (int)(f1 * 1024.0f);
            bk[2*j+1] = bb > 1023 ? 1023 : bb;
            atomicAdd(&hist[bk[2*j+1]], 1u);
        } else { bk[2*j+1] = 0; zc++; }
    }
    #pragma unroll
    for (int off = 32; off; off >>= 1) zc += __shfl_down(zc, off);
    if ((tid & 63) == 0 && zc) atomicAdd(&hist[0], (unsigned)zc);
    __syncthreads();

    if (tid < 64) {
        const int lane = tid;
        int m = attn[b * Lp + lane] + attn[b * Lp + 64 + lane];
        #pragma unroll
        for (int off = 32; off; off >>= 1) m += __shfl_down(m, off);
        m = __shfl(m, 0);
        int ml  = m - 2;
        int len = (int)((float)ml * 0.3f);
        len = len > 5 ? len : 5;
        int cap = ml * ml;
        len = len < cap ? len : cap;
        const unsigned k = (unsigned)len;

        unsigned h[16], s = 0u;
        #pragma unroll
        for (int j = 0; j < 16; j++) { h[j] = hist[16 * lane + j]; s += h[j]; }
        unsigned suf = s;
        #pragma unroll
        for (int off = 1; off < 64; off <<= 1) {
            unsigned t = __shfl_down(suf, off);
            if (lane + off < 64) suf += t;
        }
        unsigned run = suf - s;          // suffix just above this lane's bins
        int best = -1; unsigned snext = 0u;
        #pragma unroll
        for (int j = 15; j >= 0; j--) {
            unsigned nr = run + h[j];    // suffix at bin 16*lane+j
            if (best < 0 && nr >= k) { best = 16 * lane + j; snext = run; }
            run = nr;
        }
        unsigned long long msk = __ballot(best >= 0);
        int blane = 63 - __clzll(msk);
        if (lane == blane) { sh_B = (unsigned)best; sh_kk = k - snext; }
    }
    __syncthreads();

    const int B = (int)sh_B;
    const unsigned kk = sh_kk;

    #pragma unroll
    for (int i = 0; i < 16; i++) {
        if (bk[i] == B) {
            unsigned idx = atomicAdd(&sh_ccnt, 1u);
            if (idx < 2048u) cand[idx] = vu[i];
        }
    }
    __syncthreads();

    const unsigned C = sh_ccnt < 2048u ? sh_ccnt : 2048u;
    for (unsigned j = tid; j < C; j += 1024) {
        unsigned x = cand[j], g = 0u;
        for (unsigned i2 = 0; i2 < C; ++i2) g += (cand[i2] > x) ? 1u : 0u;
        if (g < kk) atomicMin(&sh_thr, x);
    }
    __syncthreads();

    const unsigned thr = sh_thr;
    float2* w2 = (float2*)arr;
    #pragma unroll
    for (int j = 0; j < 8; j++) {
        float2 r;
        r.x = (vu[2*j]   >= thr) ? 1.0f : 0.0f;
        r.y = (vu[2*j+1] >= thr) ? 1.0f : 0.0f;
        w2[tid + j * 1024] = r;
    }
}

extern "C" void kernel_launch(void* const* d_in, const int* in_sizes, int n_in,
                              void* d_out, int out_size, void* d_ws, size_t ws_size,
                              hipStream_t stream) {
    const float* table = (const float*)d_in[0];
    const int*   attn  = (const int*)d_in[1];
    const int*   labS  = (const int*)d_in[2];
    const int*   labE  = (const int*)d_in[3];
    const float* WS    = (const float*)d_in[4];
    const float* bS    = (const float*)d_in[5];
    const float* WE    = (const float*)d_in[6];
    const float* bE    = (const float*)d_in[7];
    float* out = (float*)d_out;
    float2* partial = (float2*)d_ws;

    logits_loss_kernel<<<BLOCKS, 256, 0, stream>>>(table, labS, labE, WS, bS, WE, bE,
                                                   out, partial);
    topk_predict_kernel<<<16, 1024, 0, stream>>>(attn, out, partial);
}